// Round 14
// baseline (1675.342 us; speedup 1.0000x reference)
//
#include <hip/hip_runtime.h>
#include <hip/hip_bf16.h>
#include <math.h>

#define TAU 0.5f
#define BRW 64         // rows per bucket
#define SSTRIDE 256    // segment stride (entries): 2048 B, line-aligned
#define SCAP 254       // usable capacity (mean fill ~128, +11 sigma)
#define ITERS_C 10

// ---------------------------------------------------------------------------
// CSR build v3: XCD-local binned sort, per-matrix bin pass (L2-footprint fit).
// ---------------------------------------------------------------------------
__global__ void init_kernel(int* __restrict__ cur, float* __restrict__ norms,
                            int* __restrict__ qcnt, int K, int NN, int NQ) {
    int k = blockIdx.x * 256 + threadIdx.x;
    if (k < K) cur[k] = k * SSTRIDE;
    if (k < NN) norms[k] = 0.f;
    if (k < NQ) qcnt[k] = 0;
}

__global__ void bin_kernel(const int* __restrict__ row, const int* __restrict__ col,
                           const float* __restrict__ val,
                           int* __restrict__ cur, int2* __restrict__ tmp,
                           int E, int kbase) {
    // HW_REG_XCC_ID (id=20, offset 0, size 32): imm = (31<<11)|20 = 63508.
    int xcd = __builtin_amdgcn_s_getreg(63508) & 7;
    int e = blockIdx.x * 256 + threadIdx.x;
    if (e >= E) return;
    int r = row[e];
    int k = (kbase + (r >> 6)) * 8 + xcd;
    int p = atomicAdd(&cur[k], 1);
    if (p < k * SSTRIDE + SCAP)  // 11-sigma margin; clamp prevents OOB
        tmp[p] = make_int2(col[e] | ((r & 63) << 20), __float_as_int(val[e]));
}

// Single block: bucket totals from cursors + exclusive scan over NB2 buckets.
__global__ void scan_fused_kernel(const int* __restrict__ cur,
                                  int* __restrict__ boff, int NB2) {
    __shared__ int sh[1024];
    int t = threadIdx.x;  // 1024
    int b0 = t * 4;
    int v[4];
    int s = 0;
#pragma unroll
    for (int j = 0; j < 4; ++j) {
        int b = b0 + j;
        int c = 0;
        if (b < NB2) {
#pragma unroll
            for (int i = 0; i < 8; ++i) {
                int k = b * 8 + i;
                int f = cur[k] - k * SSTRIDE;
                c += min(max(f, 0), SCAP);
            }
        }
        v[j] = c;
        s += c;
    }
    sh[t] = s;
    __syncthreads();
    for (int off = 1; off < 1024; off <<= 1) {
        int x = (t >= off) ? sh[t - off] : 0;
        __syncthreads();
        sh[t] += x;
        __syncthreads();
    }
    int run = (t == 0) ? 0 : sh[t - 1];
#pragma unroll
    for (int j = 0; j < 4; ++j) {
        int b = b0 + j;
        if (b < NB2) boff[b] = run;
        run += v[j];
    }
}

// One block per bucket: LDS-sort bucket edges by row, emit row_ptr + cv.
__global__ void place_kernel(const int* __restrict__ cur,
                             const int* __restrict__ boff,
                             const int2* __restrict__ tmp,
                             int* __restrict__ rpA, int* __restrict__ rpL,
                             int2* __restrict__ cvA, int2* __restrict__ cvL,
                             int n, int NB) {
    int b = blockIdx.x;  // 0..2*NB-1
    int m = (b >= NB) ? 1 : 0;
    int lb = b - m * NB;
    int r0 = lb * BRW;
    int r1 = min(r0 + BRW, n);
    int* rp = m ? rpL : rpA;
    int2* cv = m ? cvL : cvA;
    int lbase = m ? boff[NB] : 0;           // L's cv/rp offsets are local
    int p0 = boff[b] - lbase;
    __shared__ int cnt[BRW], curs[BRW], rbase[BRW];
    __shared__ int fill[8], fbase[9];
    __shared__ int2 stage[8 * SCAP];        // 2032 int2 = 16.3 KB
    int t = threadIdx.x;
    if (t < BRW) cnt[t] = 0;
    if (t < 8) {
        int k = b * 8 + t;
        int f = cur[k] - k * SSTRIDE;
        fill[t] = min(max(f, 0), SCAP);
    }
    __syncthreads();
    if (t == 0) {
        int r = 0;
#pragma unroll
        for (int i = 0; i < 8; ++i) { fbase[i] = r; r += fill[i]; }
        fbase[8] = r;
    }
    __syncthreads();
    int total = fbase[8];
    // coalesced per-segment load into stage + LDS row histogram
#pragma unroll
    for (int sg = 0; sg < 8; ++sg) {
        int f = fill[sg];
        const int2* src = tmp + (size_t)(b * 8 + sg) * SSTRIDE;
        int fb = fbase[sg];
        for (int i = t; i < f; i += 256) {
            int2 e = src[i];
            stage[fb + i] = e;
            atomicAdd(&cnt[(e.x >> 20) & 63], 1);
        }
    }
    __syncthreads();
    // exclusive scan over 64 row counts (wave 0, shfl ladder)
    if (t < 64) {
        int c = cnt[t];
        int sc = c;
#pragma unroll
        for (int off = 1; off < 64; off <<= 1) {
            int y = __shfl_up(sc, off, 64);
            if (t >= off) sc += y;
        }
        rbase[t] = sc - c;
        curs[t] = sc - c;
    }
    __syncthreads();
    if (t < r1 - r0) rp[r0 + t] = p0 + rbase[t];
    if (t == 0 && lb == NB - 1) rp[n] = p0 + total;  // sentinel
    __syncthreads();
    for (int i = t; i < total; i += 256) {
        int2 e = stage[i];
        int pos = atomicAdd(&curs[(e.x >> 20) & 63], 1);
        cv[p0 + pos] = make_int2(e.x & 0xFFFFF, e.y);
    }
}

// ---------------------------------------------------------------------------
// Fused GNN layer v4: one wave per row, quarter-wave float4 layout.
// At structural floor (R13): ~1 L3 line / 22 cyc / CU = MSHR+latency bound.
// ---------------------------------------------------------------------------
__global__ void fused_layer_kernel(const int* __restrict__ row_ptr,
                                   const int2* __restrict__ cv,
                                   const float* __restrict__ X,
                                   const float* __restrict__ W,
                                   float* __restrict__ Xn,
                                   float* __restrict__ s,
                                   const float* __restrict__ Wsv, int n) {
    __shared__ float Wt[64 * 68];       // Wt[k*68 + f] = W[f][k]; float4-aligned
    int tid = threadIdx.x;
    for (int i = tid; i < 4096; i += 256) {
        int j = i >> 6, k = i & 63;     // W[j,k] row-major
        Wt[k * 68 + j] = W[i];
    }
    __syncthreads();
    int lane = tid & 63;
    int ql = lane & 15;
    int q = lane >> 4;                  // quarter 0..3
    int wv = tid >> 6;
    float4 ws4 = {0.f, 0.f, 0.f, 0.f};
    if (s != nullptr) ws4 = *(const float4*)&Wsv[4 * ql];
    int nwaves = gridDim.x * 4;
    for (int row = blockIdx.x * 4 + wv; row < n; row += nwaves) {
        int p0 = row_ptr[row];
        int end = row_ptr[row + 1];
        float4 a0 = {0.f, 0.f, 0.f, 0.f}, a1 = {0.f, 0.f, 0.f, 0.f};
        float4 a2 = {0.f, 0.f, 0.f, 0.f}, a3 = {0.f, 0.f, 0.f, 0.f};
        int p = p0 + q;
        for (; p + 12 < end; p += 16) {
            int2 e0 = cv[p], e1 = cv[p + 4], e2 = cv[p + 8], e3 = cv[p + 12];
            float4 x0 = *(const float4*)&X[(size_t)e0.x * 64 + 4 * ql];
            float4 x1 = *(const float4*)&X[(size_t)e1.x * 64 + 4 * ql];
            float4 x2 = *(const float4*)&X[(size_t)e2.x * 64 + 4 * ql];
            float4 x3 = *(const float4*)&X[(size_t)e3.x * 64 + 4 * ql];
            float v0 = __int_as_float(e0.y), v1 = __int_as_float(e1.y);
            float v2 = __int_as_float(e2.y), v3 = __int_as_float(e3.y);
            a0.x += v0 * x0.x; a0.y += v0 * x0.y; a0.z += v0 * x0.z; a0.w += v0 * x0.w;
            a1.x += v1 * x1.x; a1.y += v1 * x1.y; a1.z += v1 * x1.z; a1.w += v1 * x1.w;
            a2.x += v2 * x2.x; a2.y += v2 * x2.y; a2.z += v2 * x2.z; a2.w += v2 * x2.w;
            a3.x += v3 * x3.x; a3.y += v3 * x3.y; a3.z += v3 * x3.z; a3.w += v3 * x3.w;
        }
        for (; p < end; p += 4) {
            int2 e = cv[p];
            float4 x = *(const float4*)&X[(size_t)e.x * 64 + 4 * ql];
            float v = __int_as_float(e.y);
            a0.x += v * x.x; a0.y += v * x.y; a0.z += v * x.z; a0.w += v * x.w;
        }
        float4 acc;
        acc.x = (a0.x + a1.x) + (a2.x + a3.x);
        acc.y = (a0.y + a1.y) + (a2.y + a3.y);
        acc.z = (a0.z + a1.z) + (a2.z + a3.z);
        acc.w = (a0.w + a1.w) + (a2.w + a3.w);
        acc.x += __shfl_xor(acc.x, 32, 64); acc.x += __shfl_xor(acc.x, 16, 64);
        acc.y += __shfl_xor(acc.y, 32, 64); acc.y += __shfl_xor(acc.y, 16, 64);
        acc.z += __shfl_xor(acc.z, 32, 64); acc.z += __shfl_xor(acc.z, 16, 64);
        acc.w += __shfl_xor(acc.w, 32, 64); acc.w += __shfl_xor(acc.w, 16, 64);
        float4 h4 = {0.f, 0.f, 0.f, 0.f};
        int kbase = 16 * q;
#pragma unroll
        for (int kk = 0; kk < 16; kk += 4) {
            int k = kbase + kk;
            int src = k >> 2;
            float b0 = __shfl(acc.x, src, 64);
            float b1 = __shfl(acc.y, src, 64);
            float b2 = __shfl(acc.z, src, 64);
            float b3 = __shfl(acc.w, src, 64);
            float4 w0 = *(const float4*)&Wt[(k + 0) * 68 + 4 * ql];
            float4 w1 = *(const float4*)&Wt[(k + 1) * 68 + 4 * ql];
            float4 w2 = *(const float4*)&Wt[(k + 2) * 68 + 4 * ql];
            float4 w3 = *(const float4*)&Wt[(k + 3) * 68 + 4 * ql];
            h4.x += b0 * w0.x + b1 * w1.x + b2 * w2.x + b3 * w3.x;
            h4.y += b0 * w0.y + b1 * w1.y + b2 * w2.y + b3 * w3.y;
            h4.z += b0 * w0.z + b1 * w1.z + b2 * w2.z + b3 * w3.z;
            h4.w += b0 * w0.w + b1 * w1.w + b2 * w2.w + b3 * w3.w;
        }
        h4.x += __shfl_xor(h4.x, 32, 64); h4.x += __shfl_xor(h4.x, 16, 64);
        h4.y += __shfl_xor(h4.y, 32, 64); h4.y += __shfl_xor(h4.y, 16, 64);
        h4.z += __shfl_xor(h4.z, 32, 64); h4.z += __shfl_xor(h4.z, 16, 64);
        h4.w += __shfl_xor(h4.w, 32, 64); h4.w += __shfl_xor(h4.w, 16, 64);
        float4 xv = *(const float4*)&X[(size_t)row * 64 + 4 * ql];
        float4 o;
        o.x = xv.x + fmaxf(h4.x, 0.f);
        o.y = xv.y + fmaxf(h4.y, 0.f);
        o.z = xv.z + fmaxf(h4.z, 0.f);
        o.w = xv.w + fmaxf(h4.w, 0.f);
        if (q == 0) *(float4*)&Xn[(size_t)row * 64 + 4 * ql] = o;
        if (s != nullptr) {
            float d = o.x * ws4.x + o.y * ws4.y + o.z * ws4.z + o.w * ws4.w;
#pragma unroll
            for (int off = 8; off; off >>= 1) d += __shfl_down(d, off, 16);
            if (lane == 0) s[row] = d;
        }
    }
}

// ---------------------------------------------------------------------------
// Fused power iteration v4: XCD-affinity tiling. Rows partitioned into 8
// contiguous ranges; blocks pop 64-row tiles from their OWN XCD's queue
// (cv slice ~1.6 MB -> L2-resident across iterations), then steal from
// other partitions for correctness under dispatch imbalance.
// 4 lanes/row, 4-deep load chains. Per-iteration launch (grid.sync ~134us).
// ---------------------------------------------------------------------------
__global__ void power_iter_kernel(const int* __restrict__ row_ptr,
                                  const int2* __restrict__ cv,
                                  const float* __restrict__ v_in,
                                  float* __restrict__ v_out,
                                  const float* __restrict__ norm_prev,  // 64 slots or null
                                  float* __restrict__ norm_out,         // 64 slots
                                  int* __restrict__ q,                  // 8 tile cursors
                                  int n, int PS) {
    int tid = threadIdx.x;
    int lane = tid & 63;
    float scale = 1.f;
    if (norm_prev) {
        float x = norm_prev[lane];
#pragma unroll
        for (int off = 32; off; off >>= 1) x += __shfl_xor(x, off, 64);
        scale = 1.f / fmaxf(sqrtf(x), 1e-12f);
    }
    int xcd = __builtin_amdgcn_s_getreg(63508) & 7;  // HW_REG_XCC_ID
    int rsub = tid >> 2;   // 0..63: row slot within tile
    int tl = tid & 3;      // lane within 4-wide row team
    __shared__ int sh_tile;
    __shared__ float sh[4];
    float sqacc = 0.f;
    for (int px = 0; px < 8; ++px) {
        int part = (xcd + px) & 7;
        int r0p = part * PS;
        int rows = min(PS, n - r0p);
        if (rows <= 0) continue;
        int ntiles = (rows + 63) >> 6;
        while (true) {
            __syncthreads();
            if (tid == 0) sh_tile = atomicAdd(&q[part], 1);
            __syncthreads();
            int t = sh_tile;
            if (t >= ntiles) break;
            int row = r0p + t * 64 + rsub;
            if (row < n) {
                int p = row_ptr[row] + tl;
                int end = row_ptr[row + 1];
                float s0 = 0.f, s1 = 0.f, s2 = 0.f, s3 = 0.f;
                for (; p + 12 < end; p += 16) {
                    int2 e0 = cv[p], e1 = cv[p + 4], e2 = cv[p + 8], e3 = cv[p + 12];
                    s0 += __int_as_float(e0.y) * v_in[e0.x];
                    s1 += __int_as_float(e1.y) * v_in[e1.x];
                    s2 += __int_as_float(e2.y) * v_in[e2.x];
                    s3 += __int_as_float(e3.y) * v_in[e3.x];
                }
                for (; p < end; p += 4) {
                    int2 e = cv[p];
                    s0 += __int_as_float(e.y) * v_in[e.x];
                }
                float sv = (s0 + s1) + (s2 + s3);
                sv += __shfl_xor(sv, 2, 4);
                sv += __shfl_xor(sv, 1, 4);
                if (tl == 0) {
                    float sg = (sv > 0.f) ? 1.f : ((sv < 0.f) ? -1.f : 0.f);
                    float w = sv * scale - TAU * sg;
                    v_out[row] = w;
                    sqacc += w * w;
                }
            }
        }
    }
    // block-wide norm reduction -> 64-slot partials
    for (int off = 32; off; off >>= 1) sqacc += __shfl_down(sqacc, off, 64);
    int wv = tid >> 6;
    __syncthreads();
    if (lane == 0) sh[wv] = sqacc;
    __syncthreads();
    if (tid == 0)
        atomicAdd(&norm_out[blockIdx.x & 63], sh[0] + sh[1] + sh[2] + sh[3]);
}

__global__ void finalize_kernel(const float* __restrict__ v,
                                const float* __restrict__ slots,
                                float* __restrict__ out, int n) {
    int lane = threadIdx.x & 63;
    float x = slots[lane];
#pragma unroll
    for (int off = 32; off; off >>= 1) x += __shfl_xor(x, off, 64);
    float inv = 1.f / fmaxf(sqrtf(x), 1e-12f);
    int i = blockIdx.x * 256 + threadIdx.x;
    if (i < n) out[i] = v[i] * inv;
}

extern "C" void kernel_launch(void* const* d_in, const int* in_sizes, int n_in,
                              void* d_out, int out_size, void* d_ws, size_t ws_size,
                              hipStream_t stream) {
    const int* A_row = (const int*)d_in[0];
    const int* A_col = (const int*)d_in[1];
    const float* A_val = (const float*)d_in[2];
    const int* L_row = (const int*)d_in[3];
    const int* L_col = (const int*)d_in[4];
    const float* L_val = (const float*)d_in[5];
    const float* embed = (const float*)d_in[6];
    const float* W1 = (const float*)d_in[7];
    const float* W2 = (const float*)d_in[8];
    const float* Ws = (const float*)d_in[9];
    float* out = (float*)d_out;

    const int E = in_sizes[0];
    const int D = 64;
    const int N = in_sizes[6] / D;
    const int ITERS = ITERS_C;
    const int NB = (N + BRW - 1) / BRW;   // buckets per matrix (1563)
    const int NB2 = 2 * NB;
    const int K = NB2 * 8;                // segment cursors
    // rows per XCD partition, tile-aligned (64)
    const int PS = (((N + 7) / 8) + 63) & ~63;

    char* ws = (char*)d_ws;
    size_t off = 0;
    auto carve = [&](size_t bytes) {
        void* p = ws + off;
        off += (bytes + 255) & ~(size_t)255;
        return p;
    };
    size_t feat_bytes = (size_t)N * D * sizeof(float);
    size_t tmp_bytes = (size_t)K * SSTRIDE * sizeof(int2);
    // X0/X1 and tmp share one region (tmp dead once place ran; X live after)
    char* base = (char*)carve(tmp_bytes > 2 * feat_bytes ? tmp_bytes : 2 * feat_bytes);
    float* X0 = (float*)base;
    float* X1 = (float*)(base + feat_bytes);
    int2* tmp = (int2*)base;
    int* A_rp = (int*)carve((size_t)(N + 1) * sizeof(int));
    int2* A_cv = (int2*)carve((size_t)E * sizeof(int2));
    int* L_rp = (int*)carve((size_t)(N + 1) * sizeof(int));
    int2* L_cv = (int2*)carve((size_t)E * sizeof(int2));
    int* cur = (int*)carve((size_t)K * sizeof(int));
    int* boff = (int*)carve((size_t)NB2 * sizeof(int));
    float* v_cur = (float*)carve((size_t)N * sizeof(float));
    float* v_new = (float*)carve((size_t)N * sizeof(float));
    float* norms = (float*)carve((size_t)ITERS * 64 * sizeof(float));
    int* qcnt = (int*)carve((size_t)ITERS * 8 * sizeof(int));

    int e_blocks = (E + 255) / 256;

    // ---- CSR build: XCD-local binned sort (per-matrix bin for L2 fit) ----
    init_kernel<<<(K + 255) / 256, 256, 0, stream>>>(cur, norms, qcnt,
                                                     K, ITERS * 64, ITERS * 8);
    bin_kernel<<<e_blocks, 256, 0, stream>>>(A_row, A_col, A_val, cur, tmp, E, 0);
    bin_kernel<<<e_blocks, 256, 0, stream>>>(L_row, L_col, L_val, cur, tmp, E, NB);
    scan_fused_kernel<<<1, 1024, 0, stream>>>(cur, boff, NB2);
    place_kernel<<<NB2, 256, 0, stream>>>(cur, boff, tmp,
                                          A_rp, L_rp, A_cv, L_cv, N, NB);

    // ---- two fused residual GNN layers (layer 2 also emits scores) ----
    int fl_blocks = 2048;
    fused_layer_kernel<<<fl_blocks, 256, 0, stream>>>(
        A_rp, A_cv, embed, W1, X0, nullptr, Ws, N);
    fused_layer_kernel<<<fl_blocks, 256, 0, stream>>>(
        A_rp, A_cv, X0, W2, X1, v_cur, Ws, N);

    // ---- power iterations (XCD-affinity tiles; normalize folded) ----
    int p_blocks = 1024;  // 4 blocks/CU; dynamic tile queues per XCD
    int n_blocks = (N + 255) / 256;
    float* cur_v = v_cur;
    float* nxt_v = v_new;
    for (int it = 0; it < ITERS; ++it) {
        power_iter_kernel<<<p_blocks, 256, 0, stream>>>(
            L_rp, L_cv, cur_v, nxt_v,
            it ? (norms + (it - 1) * 64) : nullptr, norms + it * 64,
            qcnt + it * 8, N, PS);
        float* t = cur_v; cur_v = nxt_v; nxt_v = t;
    }
    finalize_kernel<<<n_blocks, 256, 0, stream>>>(cur_v, norms + (ITERS - 1) * 64, out, N);
}